// Round 3
// baseline (1202.623 us; speedup 1.0000x reference)
//
#include <hip/hip_runtime.h>

// JTMPN message-passing network, MI355X.
//
// ws layout (bf16 u16 elems), total (NMESS + 2*NBND)*H u16 = 107.5 MB:
//   tree : [0, NMESS*H)                 tree_message, bf16
//   gmA  : [NMESS*H, NMESS*H+NBND*H)    graph_message ping
//   gmB  : [.., +NBND*H)                graph_message pong
// hidden (f32, NATM*H = 51.2MB) aliases gmA (dead after k_mp#3).
// binput is NOT stored: each k_mp folds fbonds@W_i^T into the GEMM k-loop
// as 2 extra K-chunks (exactly like k_atom folds fatoms@W_o_left^T).
// Output d_out is FLOAT32 (reference outputs are jnp.float32):
// [mol_vecs 2000*256 | collated 10000*256].

#define H     256
#define NBND  100000
#define NATM  50000
#define NMESS 10000
#define MAXNB 10
#define AF    35
#define BF    40      // ATOM_FDIM + BOND_FDIM
#define NPAIR 10000
#define NMOL  2000
#define APM   25
#define OF    291     // AF + H

typedef unsigned short u16;
typedef unsigned int   u32;

__device__ __forceinline__ float bflo(u32 w) { return __uint_as_float(w << 16); }
__device__ __forceinline__ float bfhi(u32 w) { return __uint_as_float(w & 0xffff0000u); }
__device__ __forceinline__ u16 f2bf(float f) {
    u32 x = __float_as_uint(f);
    return (u16)((x + 0x7fffu + ((x >> 16) & 1u)) >> 16);   // RNE
}
__device__ __forceinline__ u32 pack2(float a, float b) {
    return (u32)f2bf(a) | ((u32)f2bf(b) << 16);
}

// ---- shared 64x256-tile f32 inner product: 8x8 micro-tile per thread ----
// thread cols: {c0..c0+3} u {c0+128..c0+131}, c0=(t&31)*4; rows tr..tr+7, tr=(t>>5)*8.
__device__ __forceinline__ void gemm_inner(const float* a_lds, const float* b_lds,
                                           int tr, int c0, float acc[8][8]) {
#pragma unroll
    for (int k4 = 0; k4 < 8; ++k4) {
        float4 a4[8];
#pragma unroll
        for (int i = 0; i < 8; ++i)
            a4[i] = *(const float4*)(a_lds + (tr + i) * 32 + k4 * 4);
#pragma unroll
        for (int kk = 0; kk < 4; ++kk) {
            float4 bl = *(const float4*)(b_lds + (k4 * 4 + kk) * 256 + c0);
            float4 bh = *(const float4*)(b_lds + (k4 * 4 + kk) * 256 + c0 + 128);
            float bv[8] = {bl.x, bl.y, bl.z, bl.w, bh.x, bh.y, bh.z, bh.w};
#pragma unroll
            for (int i = 0; i < 8; ++i) {
                float av = (kk == 0) ? a4[i].x : (kk == 1) ? a4[i].y
                         : (kk == 2) ? a4[i].z : a4[i].w;
#pragma unroll
                for (int j = 0; j < 8; ++j)
                    acc[i][j] = fmaf(av, bv[j], acc[i][j]);
            }
        }
    }
}

// tree_message f32 -> bf16
__global__ __launch_bounds__(256) void k_treecvt(const float* __restrict__ tree_in,
                                                 u16* __restrict__ tree) {
    const long i = ((long)blockIdx.x * 256 + threadIdx.x) * 4;
    float4 v = *(const float4*)(tree_in + i);
    uint2 o;
    o.x = pack2(v.x, v.y);
    o.y = pack2(v.z, v.w);
    *(uint2*)(tree + i) = o;
}

// gm0 = relu(fbonds @ W_i^T). One block = 32 rows, thread = out col.
__global__ __launch_bounds__(256) void k_gm0(const float* __restrict__ fbonds,
                                             const float* __restrict__ W_i,
                                             u16* __restrict__ gm) {
    __shared__ float wi[256 * 41];   // pad 40->41
    __shared__ float fb[32 * 40];
    const int t = threadIdx.x;
    for (int i = t; i < 256 * BF; i += 256)
        wi[(i / BF) * 41 + (i % BF)] = W_i[i];
    const long r0 = (long)blockIdx.x * 32;
    for (int i = t; i < 32 * BF; i += 256)
        fb[i] = fbonds[(r0 + i / BF) * BF + (i % BF)];
    __syncthreads();
    const float* w = wi + t * 41;
    for (int rr = 0; rr < 32; ++rr) {
        float acc = 0.f;
        const float* f = fb + rr * BF;
#pragma unroll
        for (int k = 0; k < BF; ++k) acc = fmaf(f[k], w[k], acc);
        gm[(r0 + rr) * H + t] = f2bf(fmaxf(acc, 0.f));
    }
}

// one depth iteration:
//   gm_out = relu( (sum_j msg[bgraph[r][j]]) @ W_h^T  +  fbonds @ W_i^T )
// msg[idx] = tree[idx] if idx<NMESS else gm_in[idx-NMESS]; per-row pointers in LDS.
// k-loop: chunks 0..7 = gather x W_h (256 dims); chunks 8..9 = fbonds x W_i (40 dims).
__global__ __launch_bounds__(256) void k_mp(const int* __restrict__ graph,
                                            const u16* __restrict__ tree,
                                            const u16* __restrict__ gm_in,
                                            const float* __restrict__ W_h,
                                            const float* __restrict__ fbonds,
                                            const float* __restrict__ W_i,
                                            u16* __restrict__ gm_out) {
    __shared__ float a_lds[64 * 32];
    __shared__ float b_lds[32 * 256];
    __shared__ const u16* ptr_lds[64 * MAXNB];
    const int t = threadIdx.x;
    const long r0 = (long)blockIdx.x * 64;
    for (int i = t; i < 64 * MAXNB; i += 256) {
        const long r = r0 + i / MAXNB;
        const int idx = (r < NBND) ? graph[r * MAXNB + (i % MAXNB)] : 0;
        ptr_lds[i] = (idx < NMESS) ? tree + (size_t)idx * H
                                   : gm_in + (size_t)(idx - NMESS) * H;
    }
    const int c0 = (t & 31) * 4;
    const int tr = (t >> 5) * 8;
    float acc[8][8];
#pragma unroll
    for (int i = 0; i < 8; ++i)
#pragma unroll
        for (int j = 0; j < 8; ++j) acc[i][j] = 0.f;

    for (int chunk = 0; chunk < 10; ++chunk) {
        __syncthreads();
        if (chunk < 8) {
            const int kb = chunk * 32;
            // A: gathered neighbor sum, one float4 (4 k-values) per item
            for (int i = t; i < 512; i += 256) {
                const int row = i >> 3, c4 = i & 7;
                const u16* const* gp = ptr_lds + row * MAXNB;
                float4 s = {0.f, 0.f, 0.f, 0.f};
#pragma unroll
                for (int j = 0; j < MAXNB; ++j) {
                    uint2 q = *(const uint2*)(gp[j] + kb + c4 * 4);
                    s.x += bflo(q.x); s.y += bfhi(q.x);
                    s.z += bflo(q.y); s.w += bfhi(q.y);
                }
                *(float4*)(a_lds + i * 4) = s;
            }
            // B: b_lds[k][c] = W_h[c][kb+k]
#pragma unroll
            for (int k4 = 0; k4 < 8; ++k4) {
                float4 v = *(const float4*)(W_h + (long)t * H + kb + k4 * 4);
                b_lds[(k4 * 4 + 0) * 256 + t] = v.x;
                b_lds[(k4 * 4 + 1) * 256 + t] = v.y;
                b_lds[(k4 * 4 + 2) * 256 + t] = v.z;
                b_lds[(k4 * 4 + 3) * 256 + t] = v.w;
            }
        } else {
            const int kb2 = (chunk - 8) * 32;
            for (int i = t; i < 2048; i += 256) {
                const int row = i >> 5, k = i & 31;
                const long r = r0 + row;
                a_lds[i] = (r < NBND && kb2 + k < BF) ? fbonds[r * BF + kb2 + k] : 0.f;
            }
            for (int k = 0; k < 32; ++k)
                b_lds[k * 256 + t] = (kb2 + k < BF) ? W_i[(long)t * BF + kb2 + k] : 0.f;
        }
        __syncthreads();
        gemm_inner(a_lds, b_lds, tr, c0, acc);
    }
#pragma unroll
    for (int i = 0; i < 8; ++i) {
        const long r = r0 + tr + i;
        if (r < NBND) {
            uint2 o0, o1;
            o0.x = pack2(fmaxf(acc[i][0], 0.f), fmaxf(acc[i][1], 0.f));
            o0.y = pack2(fmaxf(acc[i][2], 0.f), fmaxf(acc[i][3], 0.f));
            o1.x = pack2(fmaxf(acc[i][4], 0.f), fmaxf(acc[i][5], 0.f));
            o1.y = pack2(fmaxf(acc[i][6], 0.f), fmaxf(acc[i][7], 0.f));
            *(uint2*)(gm_out + r * H + c0) = o0;
            *(uint2*)(gm_out + r * H + c0 + 128) = o1;
        }
    }
}

// collated[p] = 0.5*(gm3[i0] + gm3[i1]) -> f32 out
__global__ __launch_bounds__(256) void k_collated(const int* __restrict__ pair_idx,
                                                  const u16* __restrict__ gm,
                                                  float* __restrict__ out) {
    const int w = threadIdx.x >> 6, lane = threadIdx.x & 63;
    const long p = (long)blockIdx.x * 4 + w;
    if (p >= NPAIR) return;
    const size_t i0 = (size_t)pair_idx[p * 2 + 0];
    const size_t i1 = (size_t)pair_idx[p * 2 + 1];
    uint2 qa = *(const uint2*)(gm + i0 * H + lane * 4);
    uint2 qb = *(const uint2*)(gm + i1 * H + lane * 4);
    float4 o;
    o.x = 0.5f * (bflo(qa.x) + bflo(qb.x));
    o.y = 0.5f * (bfhi(qa.x) + bfhi(qb.x));
    o.z = 0.5f * (bflo(qa.y) + bflo(qb.y));
    o.w = 0.5f * (bfhi(qa.y) + bfhi(qb.y));
    *(float4*)(out + p * H + lane * 4) = o;
}

// atom stage: hidden = relu([fatoms | gathered nei] @ W_o^T + b_o), f32 out
__global__ __launch_bounds__(256) void k_atom(const int* __restrict__ graph,
                                              const u16* __restrict__ tree,
                                              const u16* __restrict__ gm,
                                              const float* __restrict__ fatoms,
                                              const float* __restrict__ W_o,
                                              const float* __restrict__ b_o,
                                              float* __restrict__ hidden) {
    __shared__ float a_lds[64 * 32];
    __shared__ float b_lds[32 * 256];
    __shared__ const u16* ptr_lds[64 * MAXNB];
    const int t = threadIdx.x;
    const long r0 = (long)blockIdx.x * 64;
    for (int i = t; i < 64 * MAXNB; i += 256) {
        const long r = r0 + i / MAXNB;
        const int idx = (r < NATM) ? graph[r * MAXNB + (i % MAXNB)] : 0;
        ptr_lds[i] = (idx < NMESS) ? tree + (size_t)idx * H
                                   : gm + (size_t)(idx - NMESS) * H;
    }
    const int c0 = (t & 31) * 4;
    const int tr = (t >> 5) * 8;
    float acc[8][8];
#pragma unroll
    for (int i = 0; i < 8; ++i)
#pragma unroll
        for (int j = 0; j < 8; ++j) acc[i][j] = 0.f;

    for (int chunk = 0; chunk < 10; ++chunk) {
        __syncthreads();
        if (chunk < 8) {               // nei part: ainput cols [AF, AF+256)
            const int kb = chunk * 32;
            for (int i = t; i < 512; i += 256) {
                const int row = i >> 3, c4 = i & 7;
                const u16* const* gp = ptr_lds + row * MAXNB;
                float4 s = {0.f, 0.f, 0.f, 0.f};
#pragma unroll
                for (int j = 0; j < MAXNB; ++j) {
                    uint2 q = *(const uint2*)(gp[j] + kb + c4 * 4);
                    s.x += bflo(q.x); s.y += bfhi(q.x);
                    s.z += bflo(q.y); s.w += bfhi(q.y);
                }
                *(float4*)(a_lds + i * 4) = s;
            }
            for (int k = 0; k < 32; ++k)
                b_lds[k * 256 + t] = W_o[(long)t * OF + AF + kb + k];
        } else {                       // fatoms part: ainput cols [0, AF)
            const int kb2 = (chunk - 8) * 32;
            for (int i = t; i < 2048; i += 256) {
                const int row = i >> 5, k = i & 31;
                const long r = r0 + row;
                a_lds[i] = (r < NATM && kb2 + k < AF) ? fatoms[r * AF + kb2 + k] : 0.f;
            }
            for (int k = 0; k < 32; ++k)
                b_lds[k * 256 + t] = (kb2 + k < AF) ? W_o[(long)t * OF + kb2 + k] : 0.f;
        }
        __syncthreads();
        gemm_inner(a_lds, b_lds, tr, c0, acc);
    }
    const float4 bo0 = *(const float4*)(b_o + c0);
    const float4 bo1 = *(const float4*)(b_o + c0 + 128);
#pragma unroll
    for (int i = 0; i < 8; ++i) {
        const long r = r0 + tr + i;
        if (r < NATM) {
            float4 o0, o1;
            o0.x = fmaxf(acc[i][0] + bo0.x, 0.f);
            o0.y = fmaxf(acc[i][1] + bo0.y, 0.f);
            o0.z = fmaxf(acc[i][2] + bo0.z, 0.f);
            o0.w = fmaxf(acc[i][3] + bo0.w, 0.f);
            o1.x = fmaxf(acc[i][4] + bo1.x, 0.f);
            o1.y = fmaxf(acc[i][5] + bo1.y, 0.f);
            o1.z = fmaxf(acc[i][6] + bo1.z, 0.f);
            o1.w = fmaxf(acc[i][7] + bo1.w, 0.f);
            *(float4*)(hidden + r * H + c0) = o0;
            *(float4*)(hidden + r * H + c0 + 128) = o1;
        }
    }
}

// mol_vecs[m] = mean over 25 atoms of hidden -> f32 out
__global__ __launch_bounds__(256) void k_molmean(const float* __restrict__ hidden,
                                                 float* __restrict__ out) {
    const int m = blockIdx.x, c = threadIdx.x;
    float s = 0.f;
#pragma unroll
    for (int a = 0; a < APM; ++a)
        s += hidden[((long)m * APM + a) * H + c];
    out[(long)m * H + c] = s * (1.f / APM);
}

extern "C" void kernel_launch(void* const* d_in, const int* in_sizes, int n_in,
                              void* d_out, int out_size, void* d_ws, size_t ws_size,
                              hipStream_t stream) {
    (void)in_sizes; (void)n_in; (void)out_size;
    const float* fatoms  = (const float*)d_in[0];
    const float* fbonds  = (const float*)d_in[1];
    const float* tree_in = (const float*)d_in[2];
    const int* agraph    = (const int*)d_in[3];
    const int* bgraph    = (const int*)d_in[4];
    const int* pair_idx  = (const int*)d_in[5];
    const float* W_i = (const float*)d_in[6];
    const float* W_h = (const float*)d_in[7];
    const float* W_o = (const float*)d_in[8];
    const float* b_o = (const float*)d_in[9];

    float* out = (float*)d_out;   // [mol_vecs 2000*256 | collated 10000*256], f32

    const size_t need = ((size_t)NMESS + 2 * (size_t)NBND) * H * sizeof(u16);
    if (ws_size < need) return;   // diagnostic guard: output stays 0

    u16* tree = (u16*)d_ws;
    u16* gmA  = tree + (size_t)NMESS * H;
    u16* gmB  = gmA + (size_t)NBND * H;
    float* hidden = (float*)gmA;   // gmA dead after k_mp#3

    k_treecvt<<<(NMESS * H) / 1024, 256, 0, stream>>>(tree_in, tree);
    k_gm0<<<NBND / 32, 256, 0, stream>>>(fbonds, W_i, gmA);
    k_mp<<<(NBND + 63) / 64, 256, 0, stream>>>(bgraph, tree, gmA, W_h, fbonds, W_i, gmB);
    k_mp<<<(NBND + 63) / 64, 256, 0, stream>>>(bgraph, tree, gmB, W_h, fbonds, W_i, gmA);
    k_mp<<<(NBND + 63) / 64, 256, 0, stream>>>(bgraph, tree, gmA, W_h, fbonds, W_i, gmB);
    k_collated<<<NPAIR / 4, 256, 0, stream>>>(pair_idx, gmB, out + (size_t)NMOL * H);
    k_atom<<<(NATM + 63) / 64, 256, 0, stream>>>(agraph, tree, gmB, fatoms, W_o, b_o, hidden);
    k_molmean<<<NMOL, 256, 0, stream>>>(hidden, out);
}

// Round 4
// 437.240 us; speedup vs baseline: 2.7505x; 2.7505x over previous
//
#include <hip/hip_runtime.h>

// JTMPN message-passing network, MI355X — MFMA bf16 version.
//
// ws layout (u16 units), total 107.84 MB:
//   tree    [NMESS*256]        bf16 tree messages
//   gmA     [NBND*256]         graph_message ping   (f32 'hidden' aliases here later)
//   gmB     [NBND*256]         graph_message pong
//   wfrag_h [10*16*64*8]       W_h|W_i in MFMA-frag-native bf16 layout (160 KB)
//   wfrag_o [10*16*64*8]       W_o (rotated) frag-native (160 KB)
//
// k_main<MODE>: 64-row x 256-col output tile, 256 thr = 4 waves, wave-tile 64x64.
//   MODE 0 (gm0):  relu(fbonds@W_i^T)                      -> bf16
//   MODE 1 (mp):   relu(nei_sum@W_h^T + fbonds@W_i^T)      -> bf16
//   MODE 2 (atom): relu(nei_sum@W_o'^T + fatoms@W_o''^T + b_o) -> f32
// K-steps: 0..7 = gathered nei (A1 LDS, XOR-swizzled), 8..9 = ext features (A2).
// B-frags stream from global frag-native table (L2-hot, no barriers in k-loop).

#define H     256
#define NBND  100000
#define NATM  50000
#define NMESS 10000
#define MAXNB 10
#define AF    35
#define BF    40
#define NPAIR 10000
#define NMOL  2000
#define APM   25

typedef unsigned short u16;
typedef unsigned int   u32;
using short8 = __attribute__((ext_vector_type(8))) short;
using f32x4  = __attribute__((ext_vector_type(4))) float;

__device__ __forceinline__ float bflo(u32 w) { return __uint_as_float(w << 16); }
__device__ __forceinline__ float bfhi(u32 w) { return __uint_as_float(w & 0xffff0000u); }
__device__ __forceinline__ u16 f2bf(float f) {
    u32 x = __float_as_uint(f);
    return (u16)((x + 0x7fffu + ((x >> 16) & 1u)) >> 16);   // RNE
}
__device__ __forceinline__ u32 pack2(float a, float b) {
    return (u32)f2bf(a) | ((u32)f2bf(b) << 16);
}

// tree_message f32 -> bf16
__global__ __launch_bounds__(256) void k_treecvt(const float* __restrict__ tree_in,
                                                 u16* __restrict__ tree) {
    const long i = ((long)blockIdx.x * 256 + threadIdx.x) * 4;
    float4 v = *(const float4*)(tree_in + i);
    uint2 o;
    o.x = pack2(v.x, v.y);
    o.y = pack2(v.z, v.w);
    *(uint2*)(tree + i) = o;
}

// Pack B = [Wm[:, offm:offm+256] | We[:, 0:nce] | 0-pad] (320 x 256, B[k][n])
// into frag-native: dst[((ks*16+nt)*64+lane)*8 + e] = bf16(B[ks*32+(lane>>4)*8+e][nt*16+(lane&15)])
// grid 160 blocks (ks*16+nt), 64 threads.
__global__ __launch_bounds__(64) void k_wfrag(const float* __restrict__ Wm, int ldm, int offm,
                                              const float* __restrict__ We, int lde, int nce,
                                              u16* __restrict__ dst) {
    const int t = threadIdx.x;
    const int ks = blockIdx.x >> 4, nt = blockIdx.x & 15;
    const int n = nt * 16 + (t & 15);
    u16 vals[8];
#pragma unroll
    for (int e = 0; e < 8; ++e) {
        const int k = ks * 32 + (t >> 4) * 8 + e;
        float v;
        if (k < 256)            v = Wm[(long)n * ldm + offm + k];
        else if (k - 256 < nce) v = We[(long)n * lde + (k - 256)];
        else                    v = 0.f;
        vals[e] = f2bf(v);
    }
    *(uint4*)(dst + ((size_t)blockIdx.x * 64 + t) * 8) = *(const uint4*)vals;
}

template <int MODE>   // 0: gm0, 1: mp, 2: atom
__global__ __launch_bounds__(256, 3) void k_main(
        const int* __restrict__ graph, const u16* __restrict__ tree,
        const u16* __restrict__ gm_in, const float* __restrict__ ext,
        const u16* __restrict__ wfrag, const float* __restrict__ b_o,
        u16* __restrict__ out_bf, float* __restrict__ out_f) {
    constexpr int NR  = (MODE == 2) ? NATM : NBND;
    constexpr int EXT = (MODE == 2) ? AF : BF;
    __shared__ __align__(16) u16 a1[64 * 256];   // gathered nei sums, XOR-swizzled (32 KB)
    __shared__ __align__(16) u16 a2[64 * 64];    // ext features, XOR-swizzled (8 KB)
    __shared__ int idx_lds[64 * MAXNB];

    const int t = threadIdx.x;
    const int lane = t & 63;
    const int w = t >> 6;
    const int r0 = blockIdx.x * 64;

    if (MODE != 0) {
        for (int i = t; i < 64 * MAXNB; i += 256) {
            const int r = r0 + i / MAXNB;
            idx_lds[i] = (r < NR) ? graph[(long)r * MAXNB + i % MAXNB] : 0;
        }
    }
    // A2: ext features f32 -> bf16, rows padded to 64 cols with zeros
    for (int i = t; i < 64 * 64; i += 256) {
        const int row = i >> 6, k = i & 63;
        const int r = r0 + row;
        const float v = (r < NR && k < EXT) ? ext[(long)r * EXT + k] : 0.f;
        const int bo = (row * 128 + k * 2) ^ ((row & 7) << 4);
        *(u16*)((char*)a2 + bo) = f2bf(v);
    }
    __syncthreads();

    if (MODE != 0) {
        // gather: wave w handles bonds w*16..w*16+15; lane covers dims [4*lane,4*lane+4)
        for (int bb = 0; bb < 16; ++bb) {
            const int b = w * 16 + bb;
            float s0 = 0.f, s1 = 0.f, s2 = 0.f, s3 = 0.f;
            if (r0 + b < NR) {
#pragma unroll
                for (int j = 0; j < MAXNB; ++j) {
                    const int idx = __builtin_amdgcn_readfirstlane(idx_lds[b * MAXNB + j]);
                    const u16* p = (idx < NMESS) ? tree + (size_t)idx * H
                                                 : gm_in + (size_t)(idx - NMESS) * H;
                    const uint2 q = *(const uint2*)(p + lane * 4);
                    s0 += bflo(q.x); s1 += bfhi(q.x);
                    s2 += bflo(q.y); s3 += bfhi(q.y);
                }
            }
            uint2 o;
            o.x = pack2(s0, s1);
            o.y = pack2(s2, s3);
            const int bo = (b * 512 + lane * 8) ^ ((b & 7) << 4);
            *(uint2*)((char*)a1 + bo) = o;
        }
        __syncthreads();
    }

    // ---- MFMA k-loop: no barriers (A resident, B streams from L2-hot global) ----
    f32x4 acc[4][4];
#pragma unroll
    for (int mt = 0; mt < 4; ++mt)
#pragma unroll
        for (int nt = 0; nt < 4; ++nt) acc[mt][nt] = (f32x4){0.f, 0.f, 0.f, 0.f};

    const short8* wf = (const short8*)wfrag;
    constexpr int KS0 = (MODE == 0) ? 8 : 0;
#pragma unroll
    for (int ks = KS0; ks < 10; ++ks) {
        short8 a[4], bf[4];
#pragma unroll
        for (int mt = 0; mt < 4; ++mt) {
            const int row = mt * 16 + (lane & 15);
            int bo;
            const char* base;
            if (ks < 8) { bo = (row * 512 + (ks * 32 + (lane >> 4) * 8) * 2); base = (const char*)a1; }
            else        { bo = (row * 128 + ((ks - 8) * 32 + (lane >> 4) * 8) * 2); base = (const char*)a2; }
            bo ^= (row & 7) << 4;
            a[mt] = *(const short8*)(base + bo);
        }
#pragma unroll
        for (int nt = 0; nt < 4; ++nt)
            bf[nt] = wf[((size_t)(ks * 16 + (w * 4 + nt)) * 64) + lane];
#pragma unroll
        for (int mt = 0; mt < 4; ++mt)
#pragma unroll
            for (int nt = 0; nt < 4; ++nt)
                acc[mt][nt] = __builtin_amdgcn_mfma_f32_16x16x32_bf16(a[mt], bf[nt], acc[mt][nt], 0, 0, 0);
    }

    // ---- epilogue: D frag mapping col=lane&15, row=(lane>>4)*4+reg  [m89] ----
    float bo4[4];
    if (MODE == 2) {
#pragma unroll
        for (int nt = 0; nt < 4; ++nt) bo4[nt] = b_o[w * 64 + nt * 16 + (lane & 15)];
    }
#pragma unroll
    for (int mt = 0; mt < 4; ++mt) {
#pragma unroll
        for (int nt = 0; nt < 4; ++nt) {
            const int col = w * 64 + nt * 16 + (lane & 15);
#pragma unroll
            for (int r = 0; r < 4; ++r) {
                const int row = r0 + mt * 16 + (lane >> 4) * 4 + r;
                if (row < NR) {
                    const float v = acc[mt][nt][r];
                    if (MODE == 2)
                        out_f[(size_t)row * H + col] = fmaxf(v + bo4[nt], 0.f);
                    else
                        out_bf[(size_t)row * H + col] = f2bf(fmaxf(v, 0.f));
                }
            }
        }
    }
}

// collated[p] = 0.5*(gm3[i0] + gm3[i1]) -> f32 out
__global__ __launch_bounds__(256) void k_collated(const int* __restrict__ pair_idx,
                                                  const u16* __restrict__ gm,
                                                  float* __restrict__ out) {
    const int w = threadIdx.x >> 6, lane = threadIdx.x & 63;
    const long p = (long)blockIdx.x * 4 + w;
    if (p >= NPAIR) return;
    const size_t i0 = (size_t)pair_idx[p * 2 + 0];
    const size_t i1 = (size_t)pair_idx[p * 2 + 1];
    uint2 qa = *(const uint2*)(gm + i0 * H + lane * 4);
    uint2 qb = *(const uint2*)(gm + i1 * H + lane * 4);
    float4 o;
    o.x = 0.5f * (bflo(qa.x) + bflo(qb.x));
    o.y = 0.5f * (bfhi(qa.x) + bfhi(qb.x));
    o.z = 0.5f * (bflo(qa.y) + bflo(qb.y));
    o.w = 0.5f * (bfhi(qa.y) + bfhi(qb.y));
    *(float4*)(out + p * H + lane * 4) = o;
}

// mol_vecs[m] = mean over 25 atoms of hidden -> f32 out
__global__ __launch_bounds__(256) void k_molmean(const float* __restrict__ hidden,
                                                 float* __restrict__ out) {
    const int m = blockIdx.x, c = threadIdx.x;
    float s = 0.f;
#pragma unroll
    for (int a = 0; a < APM; ++a)
        s += hidden[((long)m * APM + a) * H + c];
    out[(long)m * H + c] = s * (1.f / APM);
}

extern "C" void kernel_launch(void* const* d_in, const int* in_sizes, int n_in,
                              void* d_out, int out_size, void* d_ws, size_t ws_size,
                              hipStream_t stream) {
    (void)in_sizes; (void)n_in; (void)out_size;
    const float* fatoms  = (const float*)d_in[0];
    const float* fbonds  = (const float*)d_in[1];
    const float* tree_in = (const float*)d_in[2];
    const int* agraph    = (const int*)d_in[3];
    const int* bgraph    = (const int*)d_in[4];
    const int* pair_idx  = (const int*)d_in[5];
    const float* W_i = (const float*)d_in[6];
    const float* W_h = (const float*)d_in[7];
    const float* W_o = (const float*)d_in[8];
    const float* b_o = (const float*)d_in[9];

    float* out = (float*)d_out;   // [mol_vecs 2000*256 | collated 10000*256], f32

    const size_t WFRAG = 10 * 16 * 64 * 8;   // u16 elems per frag table
    const size_t need = ((size_t)NMESS + 2 * (size_t)NBND) * H * sizeof(u16)
                        + 2 * WFRAG * sizeof(u16);
    if (ws_size < need) return;   // diagnostic guard

    u16* tree    = (u16*)d_ws;
    u16* gmA     = tree + (size_t)NMESS * H;
    u16* gmB     = gmA + (size_t)NBND * H;
    u16* wfrag_h = gmB + (size_t)NBND * H;
    u16* wfrag_o = wfrag_h + WFRAG;
    float* hidden = (float*)gmA;   // gmA dead after k_mp#3

    const int GB = (NBND + 63) / 64;   // 1563
    const int GA = (NATM + 63) / 64;   // 782

    k_treecvt<<<(NMESS * H) / 1024, 256, 0, stream>>>(tree_in, tree);
    k_wfrag<<<160, 64, 0, stream>>>(W_h, 256, 0, W_i, BF, BF, wfrag_h);
    k_wfrag<<<160, 64, 0, stream>>>(W_o, 291, AF, W_o, 291, AF, wfrag_o);

    k_main<0><<<GB, 256, 0, stream>>>(nullptr, tree, gmA, fbonds, wfrag_h, nullptr, gmA, nullptr);
    k_main<1><<<GB, 256, 0, stream>>>(bgraph, tree, gmA, fbonds, wfrag_h, nullptr, gmB, nullptr);
    k_main<1><<<GB, 256, 0, stream>>>(bgraph, tree, gmB, fbonds, wfrag_h, nullptr, gmA, nullptr);
    k_main<1><<<GB, 256, 0, stream>>>(bgraph, tree, gmA, fbonds, wfrag_h, nullptr, gmB, nullptr);
    k_collated<<<NPAIR / 4, 256, 0, stream>>>(pair_idx, gmB, out + (size_t)NMOL * H);
    k_main<2><<<GA, 256, 0, stream>>>(agraph, tree, gmB, fatoms, wfrag_o, b_o, nullptr, hidden);
    k_molmean<<<NMOL, 256, 0, stream>>>(hidden, out);
}

// Round 5
// 371.813 us; speedup vs baseline: 3.2345x; 1.1760x over previous
//
#include <hip/hip_runtime.h>

// JTMPN message-passing network, MI355X — MFMA bf16, round 5.
//
// ws layout (u16 units), total 107.84 MB:
//   tree    [NMESS*256]        bf16 tree messages
//   gmA     [NBND*256]         graph_message ping   (f32 'hidden' aliases here later)
//   gmB     [NBND*256]         graph_message pong
//   wfrag_h [10*16*64*8]       W_h|W_i frag-native bf16 (160 KB, L2-hot)
//   wfrag_o [10*16*64*8]       W_o frag-native (160 KB)
//
// k_main<MODE>: 64-row x 256-col tile, 4 waves, wave-tile 64x64, MFMA 16x16x32.
//   MODE 0 (gm0):  relu(fbonds@W_i^T)                          -> bf16
//   MODE 1 (mp):   relu(nei_sum@W_h^T + fbonds@W_i^T)          -> bf16
//   MODE 2 (atom): relu(nei_sum@W_o'^T + fatoms@W_o''^T + b_o) -> f32
// K-steps 0..7: gathered nei (a1 LDS, XOR-swizzled); 8..9: ext feats direct
// from global to frags (no LDS). B-frags stream from frag-native table (L2).

#define H     256
#define NBND  100000
#define NATM  50000
#define NMESS 10000
#define MAXNB 10
#define AF    35
#define BF    40
#define NPAIR 10000
#define NMOL  2000
#define APM   25

typedef unsigned short u16;
typedef unsigned int   u32;
using short8 = __attribute__((ext_vector_type(8))) short;
using f32x4  = __attribute__((ext_vector_type(4))) float;

__device__ __forceinline__ float bflo(u32 w) { return __uint_as_float(w << 16); }
__device__ __forceinline__ float bfhi(u32 w) { return __uint_as_float(w & 0xffff0000u); }
__device__ __forceinline__ u16 f2bf(float f) {
    u32 x = __float_as_uint(f);
    return (u16)((x + 0x7fffu + ((x >> 16) & 1u)) >> 16);   // RNE
}
__device__ __forceinline__ u32 pack2(float a, float b) {
    return (u32)f2bf(a) | ((u32)f2bf(b) << 16);
}

// tree_message f32 -> bf16
__global__ __launch_bounds__(256) void k_treecvt(const float* __restrict__ tree_in,
                                                 u16* __restrict__ tree) {
    const long i = ((long)blockIdx.x * 256 + threadIdx.x) * 4;
    float4 v = *(const float4*)(tree_in + i);
    uint2 o;
    o.x = pack2(v.x, v.y);
    o.y = pack2(v.z, v.w);
    *(uint2*)(tree + i) = o;
}

// Pack B = [Wm[:, offm:offm+256] | We[:, 0:nce] | 0-pad] (320 x 256, B[k][n]) into
// frag-native: dst[((ks*16+nt)*64+lane)*8+e] = bf16(B[ks*32+(lane>>4)*8+e][nt*16+(lane&15)])
__global__ __launch_bounds__(64) void k_wfrag(const float* __restrict__ Wm, int ldm, int offm,
                                              const float* __restrict__ We, int lde, int nce,
                                              u16* __restrict__ dst) {
    const int t = threadIdx.x;
    const int ks = blockIdx.x >> 4, nt = blockIdx.x & 15;
    const int n = nt * 16 + (t & 15);
    u16 vals[8];
#pragma unroll
    for (int e = 0; e < 8; ++e) {
        const int k = ks * 32 + (t >> 4) * 8 + e;
        float v;
        if (k < 256)            v = Wm[(long)n * ldm + offm + k];
        else if (k - 256 < nce) v = We[(long)n * lde + (k - 256)];
        else                    v = 0.f;
        vals[e] = f2bf(v);
    }
    *(uint4*)(dst + ((size_t)blockIdx.x * 64 + t) * 8) = *(const uint4*)vals;
}

// ext features -> A-frag directly from global (ks = 8 or 9).
// frag element: row = mt*16+(lane&15) (global), cols (ks-8)*32 + (lane>>4)*8 + e.
template <int MODE>
__device__ __forceinline__ short8 ldext_frag(const float* __restrict__ ext,
                                             int rr, int lane, int ks, int NR) {
    constexpr int EXT = (MODE == 2) ? AF : BF;
    const int c0 = (ks == 9 ? 32 : 0) + ((lane >> 4) * 8);
    union { short8 s; u32 u[4]; u16 h[8]; } cv;
    cv.u[0] = cv.u[1] = cv.u[2] = cv.u[3] = 0;
    if (rr >= NR || c0 >= EXT) return cv.s;
    const float* p = ext + (size_t)rr * EXT + c0;
    if (MODE != 2) {   // BF=40: rows 160B (16-aligned), c0+8 <= 40 always when c0<40
        float4 v0 = *(const float4*)p;
        float4 v1 = *(const float4*)(p + 4);
        cv.u[0] = pack2(v0.x, v0.y);
        cv.u[1] = pack2(v0.z, v0.w);
        cv.u[2] = pack2(v1.x, v1.y);
        cv.u[3] = pack2(v1.z, v1.w);
    } else {           // AF=35: unaligned rows, possibly partial tail
#pragma unroll
        for (int e = 0; e < 8; ++e)
            cv.h[e] = (c0 + e < EXT) ? f2bf(p[e]) : (u16)0;
    }
    return cv.s;
}

template <int MODE>   // 0: gm0, 1: mp, 2: atom
__global__ __launch_bounds__(256, 4) void k_main(
        const int* __restrict__ graph, const u16* __restrict__ tree,
        const u16* __restrict__ gm_in, const float* __restrict__ ext,
        const u16* __restrict__ wfrag, const float* __restrict__ b_o,
        u16* __restrict__ out_bf, float* __restrict__ out_f) {
    constexpr int NR = (MODE == 2) ? NATM : NBND;
    __shared__ __align__(16) u16 a1[64 * 256];   // gathered nei sums, XOR-swizzled (32 KB)
    __shared__ int idx_lds[64 * MAXNB];

    const int t = threadIdx.x;
    const int lane = t & 63;
    const int w = t >> 6;
    const int r0 = blockIdx.x * 64;

    if (MODE != 0) {
        for (int i = t; i < 64 * MAXNB; i += 256) {
            const int r = r0 + i / MAXNB;
            idx_lds[i] = (r < NR) ? graph[(long)r * MAXNB + i % MAXNB] : 0;
        }
        __syncthreads();
        // gather: wave w owns rows w*16..+15; lane covers dims [4*lane, 4*lane+4)
        for (int bb = 0; bb < 16; ++bb) {
            const int b = w * 16 + bb;
            int id[MAXNB];
#pragma unroll
            for (int j = 0; j < MAXNB; ++j)
                id[j] = __builtin_amdgcn_readfirstlane(idx_lds[b * MAXNB + j]);
            float s0 = 0.f, s1 = 0.f, s2 = 0.f, s3 = 0.f;
#pragma unroll
            for (int j = 0; j < MAXNB; ++j) {
                const u16* p = (id[j] < NMESS) ? tree + (size_t)id[j] * H
                                               : gm_in + (size_t)(id[j] - NMESS) * H;
                const uint2 q = *(const uint2*)(p + lane * 4);
                s0 += bflo(q.x); s1 += bfhi(q.x);
                s2 += bflo(q.y); s3 += bfhi(q.y);
            }
            uint2 o;
            o.x = pack2(s0, s1);
            o.y = pack2(s2, s3);
            const int bo = (b * 512 + lane * 8) ^ ((b & 7) << 4);
            *(uint2*)((char*)a1 + bo) = o;
        }
        __syncthreads();
    }

    // ---- MFMA k-loop (no barriers): A from LDS/global, B streams from L2 ----
    f32x4 acc[4][4];
#pragma unroll
    for (int mt = 0; mt < 4; ++mt)
#pragma unroll
        for (int nt = 0; nt < 4; ++nt) acc[mt][nt] = (f32x4){0.f, 0.f, 0.f, 0.f};

    const short8* wf = (const short8*)wfrag;
    constexpr int KS0 = (MODE == 0) ? 8 : 0;
#pragma unroll
    for (int ks = KS0; ks < 10; ++ks) {
        short8 a[4], bf[4];
#pragma unroll
        for (int mt = 0; mt < 4; ++mt) {
            const int row = mt * 16 + (lane & 15);
            if (ks < 8) {
                const int bo = (row * 512 + (ks * 32 + (lane >> 4) * 8) * 2) ^ ((row & 7) << 4);
                a[mt] = *(const short8*)((const char*)a1 + bo);
            } else {
                a[mt] = ldext_frag<MODE>(ext, r0 + row, lane, ks, NR);
            }
        }
#pragma unroll
        for (int nt = 0; nt < 4; ++nt)
            bf[nt] = wf[((size_t)(ks * 16 + (w * 4 + nt)) * 64) + lane];
#pragma unroll
        for (int mt = 0; mt < 4; ++mt)
#pragma unroll
            for (int nt = 0; nt < 4; ++nt)
                acc[mt][nt] = __builtin_amdgcn_mfma_f32_16x16x32_bf16(a[mt], bf[nt], acc[mt][nt], 0, 0, 0);
    }

    // ---- epilogue: D frag mapping col=lane&15, row=(lane>>4)*4+reg ----
    float bo4[4];
    if (MODE == 2) {
#pragma unroll
        for (int nt = 0; nt < 4; ++nt) bo4[nt] = b_o[w * 64 + nt * 16 + (lane & 15)];
    }
#pragma unroll
    for (int mt = 0; mt < 4; ++mt) {
#pragma unroll
        for (int nt = 0; nt < 4; ++nt) {
            const int col = w * 64 + nt * 16 + (lane & 15);
#pragma unroll
            for (int r = 0; r < 4; ++r) {
                const int row = r0 + mt * 16 + (lane >> 4) * 4 + r;
                if (row < NR) {
                    const float v = acc[mt][nt][r];
                    if (MODE == 2)
                        out_f[(size_t)row * H + col] = fmaxf(v + bo4[nt], 0.f);
                    else
                        out_bf[(size_t)row * H + col] = f2bf(fmaxf(v, 0.f));
                }
            }
        }
    }
}

// collated[p] = 0.5*(gm3[i0] + gm3[i1]) -> f32 out
__global__ __launch_bounds__(256) void k_collated(const int* __restrict__ pair_idx,
                                                  const u16* __restrict__ gm,
                                                  float* __restrict__ out) {
    const int w = threadIdx.x >> 6, lane = threadIdx.x & 63;
    const long p = (long)blockIdx.x * 4 + w;
    if (p >= NPAIR) return;
    const size_t i0 = (size_t)pair_idx[p * 2 + 0];
    const size_t i1 = (size_t)pair_idx[p * 2 + 1];
    uint2 qa = *(const uint2*)(gm + i0 * H + lane * 4);
    uint2 qb = *(const uint2*)(gm + i1 * H + lane * 4);
    float4 o;
    o.x = 0.5f * (bflo(qa.x) + bflo(qb.x));
    o.y = 0.5f * (bfhi(qa.x) + bfhi(qb.x));
    o.z = 0.5f * (bflo(qa.y) + bflo(qb.y));
    o.w = 0.5f * (bfhi(qa.y) + bfhi(qb.y));
    *(float4*)(out + p * H + lane * 4) = o;
}

// mol_vecs[m] = mean over 25 atoms of hidden -> f32 out
__global__ __launch_bounds__(256) void k_molmean(const float* __restrict__ hidden,
                                                 float* __restrict__ out) {
    const int m = blockIdx.x, c = threadIdx.x;
    float s = 0.f;
#pragma unroll
    for (int a = 0; a < APM; ++a)
        s += hidden[((long)m * APM + a) * H + c];
    out[(long)m * H + c] = s * (1.f / APM);
}

extern "C" void kernel_launch(void* const* d_in, const int* in_sizes, int n_in,
                              void* d_out, int out_size, void* d_ws, size_t ws_size,
                              hipStream_t stream) {
    (void)in_sizes; (void)n_in; (void)out_size;
    const float* fatoms  = (const float*)d_in[0];
    const float* fbonds  = (const float*)d_in[1];
    const float* tree_in = (const float*)d_in[2];
    const int* agraph    = (const int*)d_in[3];
    const int* bgraph    = (const int*)d_in[4];
    const int* pair_idx  = (const int*)d_in[5];
    const float* W_i = (const float*)d_in[6];
    const float* W_h = (const float*)d_in[7];
    const float* W_o = (const float*)d_in[8];
    const float* b_o = (const float*)d_in[9];

    float* out = (float*)d_out;   // [mol_vecs 2000*256 | collated 10000*256], f32

    const size_t WFRAG = 10 * 16 * 64 * 8;   // u16 elems per frag table
    const size_t need = ((size_t)NMESS + 2 * (size_t)NBND) * H * sizeof(u16)
                        + 2 * WFRAG * sizeof(u16);
    if (ws_size < need) return;   // diagnostic guard

    u16* tree    = (u16*)d_ws;
    u16* gmA     = tree + (size_t)NMESS * H;
    u16* gmB     = gmA + (size_t)NBND * H;
    u16* wfrag_h = gmB + (size_t)NBND * H;
    u16* wfrag_o = wfrag_h + WFRAG;
    float* hidden = (float*)gmA;   // gmA dead after mp#3

    const int GB = (NBND + 63) / 64;   // 1563
    const int GA = (NATM + 63) / 64;   // 782

    k_treecvt<<<(NMESS * H) / 1024, 256, 0, stream>>>(tree_in, tree);
    k_wfrag<<<160, 64, 0, stream>>>(W_h, 256, 0, W_i, BF, BF, wfrag_h);
    k_wfrag<<<160, 64, 0, stream>>>(W_o, 291, AF, W_o, 291, AF, wfrag_o);

    k_main<0><<<GB, 256, 0, stream>>>(nullptr, tree, gmA, fbonds, wfrag_h, nullptr, gmA, nullptr);
    k_main<1><<<GB, 256, 0, stream>>>(bgraph, tree, gmA, fbonds, wfrag_h, nullptr, gmB, nullptr);
    k_main<1><<<GB, 256, 0, stream>>>(bgraph, tree, gmB, fbonds, wfrag_h, nullptr, gmA, nullptr);
    k_main<1><<<GB, 256, 0, stream>>>(bgraph, tree, gmA, fbonds, wfrag_h, nullptr, gmB, nullptr);
    k_collated<<<NPAIR / 4, 256, 0, stream>>>(pair_idx, gmB, out + (size_t)NMOL * H);
    k_main<2><<<GA, 256, 0, stream>>>(agraph, tree, gmB, fatoms, wfrag_o, b_o, nullptr, hidden);
    k_molmean<<<NMOL, 256, 0, stream>>>(hidden, out);
}